// Round 1
// baseline (69.612 us; speedup 1.0000x reference)
//
#include <hip/hip_runtime.h>

// Problem constants (from reference setup_inputs)
#define BATCH   32
#define CHANS   3
#define HW      4096      // 64*64, contiguous per (b,c) in NCHW fp32
#define NLEV    7
#define NEMBD   896
#define INNER   128       // 896 / 7
#define ROOTOFF 768       // (NLEV-1)*INNER
#define NCLS    1000

// K1: per-(b,c) mean of x[b,c,:,:]. One block of 256 threads per (b,c).
// Each thread reads 4x float4 = 16 floats (coalesced, 16B/lane).
__global__ void k_reduce_x(const float* __restrict__ x, float* __restrict__ g) {
    const int bc = blockIdx.x;                    // 0..95
    const float4* p4 = (const float4*)(x + (size_t)bc * HW);
    const int t = threadIdx.x;
    float s = 0.f;
#pragma unroll
    for (int i = 0; i < 4; ++i) {
        float4 v = p4[t + 256 * i];
        s += (v.x + v.y) + (v.z + v.w);
    }
    // wave64 reduction
#pragma unroll
    for (int off = 32; off > 0; off >>= 1)
        s += __shfl_down(s, off, 64);
    __shared__ float ls[4];
    if ((t & 63) == 0) ls[t >> 6] = s;
    __syncthreads();
    if (t == 0)
        g[bc] = (ls[0] + ls[1] + ls[2] + ls[3]) * (1.0f / HW);
}

// K2: fused folded-embedding + classifier.
// grid = (4, 32): blockIdx.y = batch, blockIdx.x = 256-wide k-chunk of 1000.
// Step A (threads 0..127): root_avg[b,j] = emb_b[768+j]
//        + sum_c g[b,c] * (sum_l emb_w[(l*3+c)*896 + 768 + j])
// Step B (all threads): out[b,k] = cls_b[k] + sum_j ra[j]*cls_w[j*1000+k]
__global__ void k_head(const float* __restrict__ g,
                       const float* __restrict__ emb_w,
                       const float* __restrict__ emb_b,
                       const float* __restrict__ cls_w,
                       const float* __restrict__ cls_b,
                       float* __restrict__ out) {
    const int b = blockIdx.y;
    const int t = threadIdx.x;
    __shared__ float ra[INNER];

    if (t < INNER) {
        float acc = emb_b[ROOTOFF + t];
#pragma unroll
        for (int c = 0; c < CHANS; ++c) {
            float w = 0.f;
#pragma unroll
            for (int l = 0; l < NLEV; ++l)
                w += emb_w[(size_t)(l * CHANS + c) * NEMBD + ROOTOFF + t];
            acc += g[b * CHANS + c] * w;   // g index is wave-uniform -> s_load
        }
        ra[t] = acc;
    }
    __syncthreads();

    const int k = blockIdx.x * blockDim.x + t;
    if (k < NCLS) {
        float acc = cls_b[k];
#pragma unroll 8
        for (int j = 0; j < INNER; ++j)
            acc += ra[j] * cls_w[(size_t)j * NCLS + k];  // coalesced across k
        out[(size_t)b * NCLS + k] = acc;
    }
}

extern "C" void kernel_launch(void* const* d_in, const int* in_sizes, int n_in,
                              void* d_out, int out_size, void* d_ws, size_t ws_size,
                              hipStream_t stream) {
    const float* x     = (const float*)d_in[0];
    const float* emb_w = (const float*)d_in[1];
    const float* emb_b = (const float*)d_in[2];
    const float* cls_w = (const float*)d_in[3];
    const float* cls_b = (const float*)d_in[4];
    float* out = (float*)d_out;
    float* g   = (float*)d_ws;   // 96 floats of scratch

    k_reduce_x<<<BATCH * CHANS, 256, 0, stream>>>(x, g);
    k_head<<<dim3(4, BATCH), 256, 0, stream>>>(g, emb_w, emb_b, cls_w, cls_b, out);
}

// Round 2
// 68.543 us; speedup vs baseline: 1.0156x; 1.0156x over previous
//
#include <hip/hip_runtime.h>

// Problem constants (from reference setup_inputs)
#define BATCH   32
#define CHANS   3
#define HW      4096      // 64*64, contiguous per (b,c) in NCHW fp32
#define NLEV    7
#define NEMBD   896
#define INNER   128       // 896 / 7
#define ROOTOFF 768       // (NLEV-1)*INNER
#define NCLS    1000

// Single fused kernel. One block per batch element, 1024 threads (16 waves).
//
// Math (exact collapse of the reference):
//   mean_{h,w} of every tree level's block-mean-repeat == global channel mean g[b,c]
//   root_avg[b,j] = emb_b[768+j] + sum_c g[b,c] * (sum_l emb_w[(l*3+c)*896 + 768+j])
//   out = root_avg @ cls_w + cls_b
//
// Phase 1: reduce x[b] (3*4096 floats). 3072 float4 / 1024 threads = 3 each,
//          and float4-index ranges [0,1024),[1024,2048),[2048,3072) are exactly
//          channels 0,1,2 — so each thread holds one partial per channel.
// Phase 2: threads 0..127 build ra[j] in LDS (folded 7-level weight sum).
// Phase 3: thread t (<1000) emits class t: 128 MACs vs L2-resident cls_w.
__global__ __launch_bounds__(1024) void k_fused(
        const float* __restrict__ x,
        const float* __restrict__ emb_w,
        const float* __restrict__ emb_b,
        const float* __restrict__ cls_w,
        const float* __restrict__ cls_b,
        float* __restrict__ out) {
    const int b = blockIdx.x;
    const int t = threadIdx.x;

    __shared__ float wsum[16][3];
    __shared__ float gsh[3];
    __shared__ float ra[INNER];

    // ---- Phase 1: per-channel sums of x[b,:,:,:] ----
    const float4* p4 = (const float4*)(x + (size_t)b * (CHANS * HW));
    float4 v0 = p4[t];           // channel 0
    float4 v1 = p4[t + 1024];    // channel 1
    float4 v2 = p4[t + 2048];    // channel 2
    float s0 = (v0.x + v0.y) + (v0.z + v0.w);
    float s1 = (v1.x + v1.y) + (v1.z + v1.w);
    float s2 = (v2.x + v2.y) + (v2.z + v2.w);
#pragma unroll
    for (int off = 32; off > 0; off >>= 1) {
        s0 += __shfl_down(s0, off, 64);
        s1 += __shfl_down(s1, off, 64);
        s2 += __shfl_down(s2, off, 64);
    }
    const int wave = t >> 6;
    if ((t & 63) == 0) {
        wsum[wave][0] = s0; wsum[wave][1] = s1; wsum[wave][2] = s2;
    }
    __syncthreads();
    if (t < CHANS) {
        float acc = 0.f;
#pragma unroll
        for (int w = 0; w < 16; ++w) acc += wsum[w][t];
        gsh[t] = acc * (1.0f / HW);
    }
    __syncthreads();

    // ---- Phase 2: folded root embedding row ----
    if (t < INNER) {
        float acc = emb_b[ROOTOFF + t];
#pragma unroll
        for (int c = 0; c < CHANS; ++c) {
            float w = 0.f;
#pragma unroll
            for (int l = 0; l < NLEV; ++l)
                w += emb_w[(size_t)(l * CHANS + c) * NEMBD + ROOTOFF + t];
            acc += gsh[c] * w;
        }
        ra[t] = acc;
    }
    __syncthreads();

    // ---- Phase 3: classifier row for this batch ----
    if (t < NCLS) {
        float acc = cls_b[t];
#pragma unroll 8
        for (int j = 0; j < INNER; ++j)
            acc += ra[j] * cls_w[(size_t)j * NCLS + t];   // coalesced across t
        out[(size_t)b * NCLS + t] = acc;
    }
}

extern "C" void kernel_launch(void* const* d_in, const int* in_sizes, int n_in,
                              void* d_out, int out_size, void* d_ws, size_t ws_size,
                              hipStream_t stream) {
    const float* x     = (const float*)d_in[0];
    const float* emb_w = (const float*)d_in[1];
    const float* emb_b = (const float*)d_in[2];
    const float* cls_w = (const float*)d_in[3];
    const float* cls_b = (const float*)d_in[4];
    float* out = (float*)d_out;

    k_fused<<<BATCH, 1024, 0, stream>>>(x, emb_w, emb_b, cls_w, cls_b, out);
}

// Round 3
// 64.926 us; speedup vs baseline: 1.0722x; 1.0557x over previous
//
#include <hip/hip_runtime.h>

// Problem constants (from reference setup_inputs)
#define BATCH   32
#define CHANS   3
#define HW      4096      // 64*64, contiguous per (b,c) in NCHW fp32
#define NLEV    7
#define NEMBD   896
#define INNER   128       // 896 / 7
#define ROOTOFF 768       // (NLEV-1)*INNER
#define NCLS    1000

// Exact collapse of the reference:
//   g[b,c]     = mean_{h,w} x[b,c,h,w]        (every tree level's hw-mean == g)
//   wfold[c,j] = sum_l emb_w[(l*3+c)*896 + 768+j]
//   ebias[j]   = emb_b[768+j]
//   out[b,k]   = d[k] + sum_c g[b,c]*M[c,k]
//     M[c,k]   = sum_j wfold[c,j]*cls_w[j*1000+k]   (batch-independent!)
//     d[k]     = cls_b[k] + sum_j ebias[j]*cls_w[j*1000+k]
// => cls_w is read exactly once (512 KB total), not once per batch.

// K1: per-(b,c) mean of x. 96 blocks x 256 threads, 16 floats/thread.
__global__ void k_reduce_x(const float* __restrict__ x, float* __restrict__ g) {
    const int bc = blockIdx.x;                    // 0..95
    const float4* p4 = (const float4*)(x + (size_t)bc * HW);
    const int t = threadIdx.x;
    float s = 0.f;
#pragma unroll
    for (int i = 0; i < 4; ++i) {
        float4 v = p4[t + 256 * i];
        s += (v.x + v.y) + (v.z + v.w);
    }
#pragma unroll
    for (int off = 32; off > 0; off >>= 1)
        s += __shfl_down(s, off, 64);
    __shared__ float ls[4];
    if ((t & 63) == 0) ls[t >> 6] = s;
    __syncthreads();
    if (t == 0)
        g[bc] = (ls[0] + ls[1] + ls[2] + ls[3]) * (1.0f / HW);
}

// K2: batch-factored head. grid = 63 blocks x 256 threads.
// tx = t&15 -> one of 16 columns (k = blk*16+tx); ty = t>>4 -> one of 16
// j-slices (8 j's each). Each thread issues its 8 cls_w loads up front
// (all in flight -> one HBM latency round), partials reduced in LDS,
// then all threads fan the 32 batch-rows out (2 stores/thread).
__global__ __launch_bounds__(256) void k_head(
        const float* __restrict__ g,
        const float* __restrict__ emb_w,
        const float* __restrict__ emb_b,
        const float* __restrict__ cls_w,
        const float* __restrict__ cls_b,
        float* __restrict__ out) {
    const int t  = threadIdx.x;
    const int tx = t & 15;
    const int ty = t >> 4;
    const int k  = blockIdx.x * 16 + tx;
    const bool kok = (k < NCLS);

    __shared__ float wf0[INNER], wf1[INNER], wf2[INNER], eb[INNER];
    __shared__ float gsh[BATCH * CHANS];
    __shared__ float4 red[16][16];     // [ty][tx] partial (m0,m1,m2,d)
    __shared__ float4 fin[16];         // [tx] reduced

    // cooperative prep: folded weights + bias + g
    if (t < INNER) {
        float a0 = 0.f, a1 = 0.f, a2 = 0.f;
#pragma unroll
        for (int l = 0; l < NLEV; ++l) {
            const float* row = emb_w + (size_t)(l * CHANS) * NEMBD + ROOTOFF + t;
            a0 += row[0 * NEMBD];
            a1 += row[1 * NEMBD];
            a2 += row[2 * NEMBD];
        }
        wf0[t] = a0; wf1[t] = a1; wf2[t] = a2;
        eb[t]  = emb_b[ROOTOFF + t];
    } else if (t < INNER + BATCH * CHANS) {
        gsh[t - INNER] = g[t - INNER];
    }
    __syncthreads();

    // partial M/d over this thread's 8 j's
    float m0 = 0.f, m1 = 0.f, m2 = 0.f, dd = 0.f;
    if (kok) {
        const int jb = ty * 8;
        float w[8];
#pragma unroll
        for (int jj = 0; jj < 8; ++jj)
            w[jj] = cls_w[(size_t)(jb + jj) * NCLS + k];
#pragma unroll
        for (int jj = 0; jj < 8; ++jj) {
            const int j = jb + jj;
            m0 += wf0[j] * w[jj];
            m1 += wf1[j] * w[jj];
            m2 += wf2[j] * w[jj];
            dd += eb[j]  * w[jj];
        }
    }
    red[ty][tx] = make_float4(m0, m1, m2, dd);
    __syncthreads();

    if (ty == 0) {
        float4 a = make_float4(0.f, 0.f, 0.f, kok ? cls_b[k] : 0.f);
#pragma unroll
        for (int yy = 0; yy < 16; ++yy) {
            float4 p = red[yy][tx];
            a.x += p.x; a.y += p.y; a.z += p.z; a.w += p.w;
        }
        fin[tx] = a;
    }
    __syncthreads();

    // fan-out: thread (tx,ty) writes batches b=ty and b=ty+16 for column k
    if (kok) {
        const float4 m = fin[tx];
#pragma unroll
        for (int h = 0; h < 2; ++h) {
            const int b = ty + 16 * h;
            const float* gb = gsh + b * CHANS;
            out[(size_t)b * NCLS + k] = m.w + gb[0] * m.x + gb[1] * m.y + gb[2] * m.z;
        }
    }
}

extern "C" void kernel_launch(void* const* d_in, const int* in_sizes, int n_in,
                              void* d_out, int out_size, void* d_ws, size_t ws_size,
                              hipStream_t stream) {
    const float* x     = (const float*)d_in[0];
    const float* emb_w = (const float*)d_in[1];
    const float* emb_b = (const float*)d_in[2];
    const float* cls_w = (const float*)d_in[3];
    const float* cls_b = (const float*)d_in[4];
    float* out = (float*)d_out;
    float* g   = (float*)d_ws;   // 96 floats of scratch

    k_reduce_x<<<BATCH * CHANS, 256, 0, stream>>>(x, g);
    k_head<<<(NCLS + 15) / 16, 256, 0, stream>>>(g, emb_w, emb_b, cls_w, cls_b, out);
}